// Round 12
// baseline (18773.741 us; speedup 1.0000x reference)
//
#include <hip/hip_runtime.h>
#include <hip/hip_fp16.h>
#include <stdint.h>

// Problem: x[16,2048,512] f32, embed[4096,512] f32.
// encode: idx[n] = argmax_k (x.e_k - 0.5||e_k||^2); decode: embed[idx].
// d_out (float): [0,32768) = idx, [32768,+32768*512) = quantize.
//
// R12 = R11 with the split-collision fixed: blocks (brow,nsp=0/1) cover
// different code halves of the SAME rows, so they must NOT both write
// outIdx. Each block writes its merged per-(row,nsp) top-3 to global
// partials; reduce_top3 merges the two splits, emits idx + ambiguity lists.
// GEMM: 64 barrier-pairs x 64 MFMA/wave (BM=256,BN=256,BK=64, single
// __syncthreads dbuf skeleton), acc init = -0.5||e||^2, LDS running top-3.
// Stage 2: fixupA exact f64 on {i1,i2}; fixupB full scan (rare).

typedef _Float16 f16;
typedef __attribute__((ext_vector_type(4))) _Float16 f16x4;
typedef __attribute__((ext_vector_type(8))) _Float16 f16x8;
typedef __attribute__((ext_vector_type(4))) float f32x4;

#define DDIM 512
#define KCODES 4096
#define NSPLIT 2
#define BM 256
#define BN 256
#define BK 64
#define NCHUNK ((KCODES / NSPLIT) / BN)  // 8
#define NSTEP (NCHUNK * (DDIM / BK))     // 64 barrier-pairs
#define BAND 0.25f
#define CAPB 4096

__device__ __forceinline__ void gload_lds16(const void* g, void* l) {
  __builtin_amdgcn_global_load_lds(
      (const __attribute__((address_space(1))) void*)g,
      (__attribute__((address_space(3))) void*)l, 16, 0, 0);
}

// -------- conversion: f32 -> hi f16 ------------------------------------------
__global__ void convert_hi(const float* __restrict__ in, f16* __restrict__ hi, int n4) {
  int stride = gridDim.x * blockDim.x;
  for (int i = blockIdx.x * blockDim.x + threadIdx.x; i < n4; i += stride) {
    float4 v = ((const float4*)in)[i];
    f16x4 h;
    h[0] = (_Float16)v.x; h[1] = (_Float16)v.y;
    h[2] = (_Float16)v.z; h[3] = (_Float16)v.w;
    ((f16x4*)hi)[i] = h;
  }
}

// -------- esqh = 0.5*||e||^2 --------------------------------------------------
__global__ void esq_kernel(const float* __restrict__ e, float* __restrict__ esqh) {
  int gw = (blockIdx.x * blockDim.x + threadIdx.x) >> 6;
  int lane = threadIdx.x & 63;
  if (gw >= KCODES) return;
  const float4* row = (const float4*)(e + (size_t)gw * DDIM);
  float4 a = row[lane * 2];
  float4 b = row[lane * 2 + 1];
  double s = (double)a.x * a.x + (double)a.y * a.y + (double)a.z * a.z + (double)a.w * a.w +
             (double)b.x * b.x + (double)b.y * b.y + (double)b.z * b.z + (double)b.w * b.w;
#pragma unroll
  for (int m = 32; m; m >>= 1) s += __shfl_xor(s, m, 64);
  if (lane == 0) esqh[gw] = (float)(0.5 * s);
}

__global__ void zero2(int* c) { c[0] = 0; c[1] = 0; }

// -------- stage 1 ------------------------------------------------------------
// grid = 128*NSPLIT = 256 blocks (1/CU), 512 thr (8 waves: 4 row x 2 code).
// LDS: dbuf 2 x { A[256][128B] @0, B[256][128B] @32768 } = 128K, XOR swizzle
// byte ^= (row&7)<<4 on both; running top-3 scratch 16K @131072.
// Output: parts[(row*NSPLIT+nsp)] = 2 float4 {v1,i1,v2,i2},{v3,-,-,-}.
__global__ __launch_bounds__(512, 1) void vq_main(
    const f16* __restrict__ Ah, const f16* __restrict__ Bh,
    const float* __restrict__ esqh, float4* __restrict__ parts, int nRowBlocks) {
  __shared__ char lds[147456];
  const int tid = threadIdx.x;
  const int lane = tid & 63;
  const int wv = tid >> 6;
  const int wr = wv >> 1;     // 0..3: 64-row group
  const int wc = wv & 1;      // 0..1: 128-code group
  const int l15 = lane & 15, lg = lane >> 4;

  int nwg = gridDim.x, bid = blockIdx.x;
  int cpx = nwg >> 3;                      // nwg % 8 == 0
  int swzb = (bid & 7) * cpx + (bid >> 3); // XCD-aware swizzle (bijective)
  int nsp = swzb / nRowBlocks;
  int brow = swzb % nRowBlocks;
  int rowbase = brow * BM;
  const int codesPer = KCODES / NSPLIT;    // 2048
  const int csplit = nsp * codesPer;

  // staging: 8 threads/row, rows srow + r*64; source column pre-XORed
  const int srow = tid >> 3;                               // 0..63
  const int sXor = ((tid & 7) * 16) ^ ((srow & 7) << 4);   // bytes in 128B row
  const f16* aS = Ah + (size_t)(rowbase + srow) * DDIM + (sXor >> 1);
  const f16* bS = Bh + (size_t)(csplit + srow) * DDIM + (sXor >> 1);

  // LDS read offsets (swizzled): element K at row*128 + (Kbytes ^ (row&7)<<4)
  const int colOff0 = (lg * 16) ^ ((l15 & 7) << 4);
  const int colOff1 = (64 + lg * 16) ^ ((l15 & 7) << 4);
  const int aRB = (wr * 64 + l15) * 128;
  const int bRB = 32768 + (wc * 128 + l15) * 128;
  float* scratch = (float*)(lds + 131072);  // [256 rows][2 wc][8 floats]

  f32x4 acc[4][8];

  // prologue: stage pair 0 into buf 0
  {
    char* dst = lds + wv * 1024;
#pragma unroll
    for (int r = 0; r < 4; ++r) {
      gload_lds16(aS + (size_t)(r * 64) * DDIM, dst + r * 8192);
      gload_lds16(bS + (size_t)(r * 64) * DDIM, dst + 32768 + r * 8192);
    }
  }
  __syncthreads();

#pragma unroll 1
  for (int s = 0; s < NSTEP; ++s) {
    const int ch = s >> 3, p = s & 7, cur = s & 1;
    float esqv[8];
    if (p == 0) {  // compiler-tracked; issued before stage
#pragma unroll
      for (int j = 0; j < 8; ++j)
        esqv[j] = esqh[csplit + ch * BN + wc * 128 + j * 16 + l15];
    }
    if (s + 1 < NSTEP) {  // stage next pair into other buffer
      const int ns = s + 1;
      const int kk = (ns & 7) * BK;
      const size_t bo = (size_t)(ns >> 3) * ((size_t)BN * DDIM) + kk;
      char* dst = lds + (ns & 1) * 65536 + wv * 1024;
#pragma unroll
      for (int r = 0; r < 4; ++r) {
        gload_lds16(aS + (size_t)(r * 64) * DDIM + kk, dst + r * 8192);
        gload_lds16(bS + (size_t)(r * 64) * DDIM + bo, dst + 32768 + r * 8192);
      }
    }
    if (p == 0) {  // acc = -0.5*||e||^2
#pragma unroll
      for (int j = 0; j < 8; ++j) {
        float e = -esqv[j];
#pragma unroll
        for (int i = 0; i < 4; ++i) acc[i][j] = (f32x4){e, e, e, e};
      }
    }

    const char* base = lds + cur * 65536;
    {  // k-subtile 0
      f16x8 af[4];
#pragma unroll
      for (int i = 0; i < 4; ++i) af[i] = *(const f16x8*)(base + aRB + i * 2048 + colOff0);
#pragma unroll
      for (int j = 0; j < 8; ++j) {
        f16x8 bf = *(const f16x8*)(base + bRB + j * 2048 + colOff0);
#pragma unroll
        for (int i = 0; i < 4; ++i)
          acc[i][j] = __builtin_amdgcn_mfma_f32_16x16x32_f16(af[i], bf, acc[i][j], 0, 0, 0);
      }
    }
    {  // k-subtile 1
      f16x8 af[4];
#pragma unroll
      for (int i = 0; i < 4; ++i) af[i] = *(const f16x8*)(base + aRB + i * 2048 + colOff1);
#pragma unroll
      for (int j = 0; j < 8; ++j) {
        f16x8 bf = *(const f16x8*)(base + bRB + j * 2048 + colOff1);
#pragma unroll
        for (int i = 0; i < 4; ++i)
          acc[i][j] = __builtin_amdgcn_mfma_f32_16x16x32_f16(af[i], bf, acc[i][j], 0, 0, 0);
      }
    }

    if (p == 7) {  // chunk epilogue: transient top-3 -> butterfly -> LDS merge
      float v1[16], v2[16], v3[16];
      int i1[16], i2[16];
#pragma unroll
      for (int t = 0; t < 16; ++t) { v1[t] = v2[t] = v3[t] = -3.4e38f; i1[t] = i2[t] = 0; }
#pragma unroll
      for (int j = 0; j < 8; ++j) {
        const int code = csplit + ch * BN + wc * 128 + j * 16 + l15;
#pragma unroll
        for (int i = 0; i < 4; ++i)
#pragma unroll
          for (int r = 0; r < 4; ++r) {
            float v = acc[i][j][r];
            int t = i * 4 + r;
            if (v > v1[t]) { v3[t] = v2[t]; v2[t] = v1[t]; i2[t] = i1[t]; v1[t] = v; i1[t] = code; }
            else if (v > v2[t]) { v3[t] = v2[t]; v2[t] = v; i2[t] = code; }
            else if (v > v3[t]) v3[t] = v;
          }
      }
      // butterfly over 16 l15 lanes (same rows, different codes)
#pragma unroll
      for (int m = 1; m < 16; m <<= 1) {
#pragma unroll
        for (int t = 0; t < 16; ++t) {
          float ov1 = __shfl_xor(v1[t], m, 64);
          int oi1 = __shfl_xor(i1[t], m, 64);
          float ov2 = __shfl_xor(v2[t], m, 64);
          int oi2 = __shfl_xor(i2[t], m, 64);
          float ov3 = __shfl_xor(v3[t], m, 64);
          if (ov1 > v1[t] || (ov1 == v1[t] && oi1 < i1[t])) {
            if (v1[t] > ov2 || (v1[t] == ov2 && i1[t] < oi2)) {
              v3[t] = fmaxf(ov2, v2[t]); v2[t] = v1[t]; i2[t] = i1[t];
            } else {
              v3[t] = fmaxf(v1[t], ov3); v2[t] = ov2; i2[t] = oi2;
            }
            v1[t] = ov1; i1[t] = oi1;
          } else {
            if (ov1 > v2[t] || (ov1 == v2[t] && oi1 < i2[t])) {
              v3[t] = fmaxf(v2[t], ov2); v2[t] = ov1; i2[t] = oi1;
            } else {
              v3[t] = fmaxf(ov1, v3[t]);
            }
          }
        }
      }
      if (l15 == 0) {  // merge into running per-(row,wc) slot — wave-private
#pragma unroll
        for (int t = 0; t < 16; ++t) {
          int rloc = wr * 64 + (t >> 2) * 16 + lg * 4 + (t & 3);
          float* e = scratch + (rloc * 2 + wc) * 8;
          if (ch == 0) {
            e[0] = v1[t]; e[1] = __int_as_float(i1[t]);
            e[2] = v2[t]; e[3] = __int_as_float(i2[t]);
            e[4] = v3[t];
          } else {
            float m1 = e[0], m2 = e[2], m3 = e[4];
            int j1 = __float_as_int(e[1]), j2 = __float_as_int(e[3]);
            float o1, o2, o3; int oi1, oi2;
            if (m1 >= v1[t]) {  // stored = older chunk = lower code: wins ties
              o1 = m1; oi1 = j1;
              if (m2 >= v1[t]) { o2 = m2; oi2 = j2; o3 = fmaxf(m3, v1[t]); }
              else { o2 = v1[t]; oi2 = i1[t]; o3 = fmaxf(m2, v2[t]); }
            } else {
              o1 = v1[t]; oi1 = i1[t];
              if (v2[t] > m1) { o2 = v2[t]; oi2 = i2[t]; o3 = fmaxf(v3[t], m1); }
              else { o2 = m1; oi2 = j1; o3 = fmaxf(v2[t], m2); }
            }
            e[0] = o1; e[1] = __int_as_float(oi1);
            e[2] = o2; e[3] = __int_as_float(oi2);
            e[4] = o3;
          }
        }
      }
    }
    __syncthreads();
  }

  // ---- final: merge 2 wc-slots per row -> GLOBAL partials (per row,nsp) -----
  // (R11 bug: writing outIdx here let the other nsp-block clobber it.)
  if (tid < BM) {
    const float* e0 = scratch + (tid * 2) * 8;
    const float* e1 = scratch + (tid * 2 + 1) * 8;
    float a1 = e0[0], a2 = e0[2], a3 = e0[4];
    int ai1 = __float_as_int(e0[1]), ai2 = __float_as_int(e0[3]);
    float b1 = e1[0], b2 = e1[2], b3 = e1[4];
    int bi1 = __float_as_int(e1[1]), bi2 = __float_as_int(e1[3]);
    float m1, m2, m3; int j1, j2;
    bool aw = (a1 > b1) || (a1 == b1 && ai1 < bi1);
    if (aw) {
      m1 = a1; j1 = ai1;
      if (a2 > b1 || (a2 == b1 && ai2 < bi1)) { m2 = a2; j2 = ai2; m3 = fmaxf(a3, b1); }
      else { m2 = b1; j2 = bi1; m3 = fmaxf(a2, b2); }
    } else {
      m1 = b1; j1 = bi1;
      if (b2 > a1 || (b2 == a1 && bi2 < ai1)) { m2 = b2; j2 = bi2; m3 = fmaxf(b3, a1); }
      else { m2 = a1; j2 = ai1; m3 = fmaxf(b2, a2); }
    }
    size_t slot = ((size_t)(rowbase + tid) * NSPLIT + nsp) * 2;
    parts[slot] = make_float4(m1, __int_as_float(j1), m2, __int_as_float(j2));
    parts[slot + 1] = make_float4(m3, 0.f, 0.f, 0.f);
  }
}

// -------- reduce: merge NSPLIT partials per row, emit idx + lists ------------
__global__ void reduce_top3(const float4* __restrict__ parts,
                            float* __restrict__ outIdx,
                            int4* __restrict__ listA, int* __restrict__ listB,
                            int* __restrict__ cnts, int nRows) {
  int row = blockIdx.x * blockDim.x + threadIdx.x;
  if (row >= nRows) return;
  size_t s0 = (size_t)row * NSPLIT * 2;
  float4 a0 = parts[s0], ax = parts[s0 + 1];
  float4 b0 = parts[s0 + 2], bx = parts[s0 + 3];
  float a1 = a0.x, a2 = a0.z, a3 = ax.x;
  int ai1 = __float_as_int(a0.y), ai2 = __float_as_int(a0.w);
  float b1 = b0.x, b2 = b0.z, b3 = bx.x;
  int bi1 = __float_as_int(b0.y), bi2 = __float_as_int(b0.w);
  float m1, m2, m3; int j1, j2;
  bool aw = (a1 > b1) || (a1 == b1 && ai1 < bi1);
  if (aw) {
    m1 = a1; j1 = ai1;
    if (a2 > b1 || (a2 == b1 && ai2 < bi1)) { m2 = a2; j2 = ai2; m3 = fmaxf(a3, b1); }
    else { m2 = b1; j2 = bi1; m3 = fmaxf(a2, b2); }
  } else {
    m1 = b1; j1 = bi1;
    if (b2 > a1 || (b2 == a1 && bi2 < ai1)) { m2 = b2; j2 = bi2; m3 = fmaxf(b3, a1); }
    else { m2 = a1; j2 = ai1; m3 = fmaxf(b2, a2); }
  }
  outIdx[row] = (float)j1;
  if (m1 - m2 <= BAND) { int p = atomicAdd(&cnts[0], 1); listA[p] = make_int4(row, j1, j2, 0); }
  if (m1 - m3 <= BAND) { int p = atomicAdd(&cnts[1], 1); listB[p] = row; }
}

#define DOT8(s, xa, xb, ea, eb)                                    \
  s += ((double)xa.x - 0.5 * (double)ea.x) * (double)ea.x;         \
  s += ((double)xa.y - 0.5 * (double)ea.y) * (double)ea.y;         \
  s += ((double)xa.z - 0.5 * (double)ea.z) * (double)ea.z;         \
  s += ((double)xa.w - 0.5 * (double)ea.w) * (double)ea.w;         \
  s += ((double)xb.x - 0.5 * (double)eb.x) * (double)eb.x;         \
  s += ((double)xb.y - 0.5 * (double)eb.y) * (double)eb.y;         \
  s += ((double)xb.z - 0.5 * (double)eb.z) * (double)eb.z;         \
  s += ((double)xb.w - 0.5 * (double)eb.w) * (double)eb.w;

// -------- fixupA: exact f64 re-score of {i1,i2}, one wave per entry ----------
__global__ void fixupA(const float* __restrict__ x, const float* __restrict__ embed,
                       const int* __restrict__ cnts, const int4* __restrict__ listA,
                       float* __restrict__ outIdx) {
  int gw = (blockIdx.x * blockDim.x + threadIdx.x) >> 6;
  int lane = threadIdx.x & 63;
  int nw = (gridDim.x * blockDim.x) >> 6;
  int n = cnts[0];
  for (int u = gw; u < n; u += nw) {
    int4 e = listA[u];
    const float4* xp = (const float4*)(x + (size_t)e.x * DDIM);
    float4 xa = xp[lane * 2], xb = xp[lane * 2 + 1];
    double d0, d1;
    {
      const float4* ep = (const float4*)(embed + (size_t)e.y * DDIM);
      float4 ea = ep[lane * 2], eb = ep[lane * 2 + 1];
      double s = 0.0; DOT8(s, xa, xb, ea, eb);
#pragma unroll
      for (int m = 32; m; m >>= 1) s += __shfl_xor(s, m, 64);
      d0 = s;
    }
    {
      const float4* ep = (const float4*)(embed + (size_t)e.z * DDIM);
      float4 ea = ep[lane * 2], eb = ep[lane * 2 + 1];
      double s = 0.0; DOT8(s, xa, xb, ea, eb);
#pragma unroll
      for (int m = 32; m; m >>= 1) s += __shfl_xor(s, m, 64);
      d1 = s;
    }
    if (lane == 0) {
      int best = (d1 > d0 || (d1 == d0 && e.z < e.y)) ? e.z : e.y;
      outIdx[e.x] = (float)best;
    }
  }
}

// -------- fixupB: full exact scan for rare rows; 8 blocks/row + merge --------
__global__ __launch_bounds__(256) void fixupB(
    const float* __restrict__ x, const float* __restrict__ embed,
    const int* __restrict__ cnts, const int* __restrict__ listB,
    double2* __restrict__ fbParts) {
  __shared__ double sv[4];
  __shared__ int si[4];
  int tid = threadIdx.x, lane = tid & 63, wv = tid >> 6;
  int nB = cnts[1]; if (nB > CAPB) nB = CAPB;
  for (int u = blockIdx.x; u < nB * 8; u += gridDim.x) {
    int entry = u >> 3, oct = u & 7;
    int row = listB[entry];
    const float4* xp = (const float4*)(x + (size_t)row * DDIM);
    float4 xa = xp[lane * 2], xb = xp[lane * 2 + 1];
    double bv = -1e300; int bi = 0;
    int cbase = oct * 512 + wv * 128;
#pragma unroll 1
    for (int k = 0; k < 128; ++k) {
      int c = cbase + k;
      const float4* ep = (const float4*)(embed + (size_t)c * DDIM);
      float4 ea = ep[lane * 2], eb = ep[lane * 2 + 1];
      double s = 0.0; DOT8(s, xa, xb, ea, eb);
#pragma unroll
      for (int m = 32; m; m >>= 1) s += __shfl_xor(s, m, 64);
      if (s > bv) { bv = s; bi = c; }
    }
    if (lane == 0) { sv[wv] = bv; si[wv] = bi; }
    __syncthreads();
    if (tid == 0) {
      double b = sv[0]; int bidx = si[0];
#pragma unroll
      for (int w = 1; w < 4; ++w)
        if (sv[w] > b || (sv[w] == b && si[w] < bidx)) { b = sv[w]; bidx = si[w]; }
      fbParts[entry * 8 + oct] = make_double2(b, (double)bidx);
    }
    __syncthreads();
  }
}

__global__ void fixupB2(const int* __restrict__ cnts, const int* __restrict__ listB,
                        const double2* __restrict__ fbParts, float* __restrict__ outIdx) {
  int nB = cnts[1]; if (nB > CAPB) nB = CAPB;
  for (int e = threadIdx.x; e < nB; e += blockDim.x) {
    double bv = -1e300; int bi = 0;
#pragma unroll
    for (int q = 0; q < 8; ++q) {
      double2 p = fbParts[e * 8 + q];
      int pi = (int)p.y;
      if (p.x > bv || (p.x == bv && pi < bi)) { bv = p.x; bi = pi; }
    }
    outIdx[listB[e]] = (float)bi;
  }
}

// -------- decode gather ------------------------------------------------------
__global__ void decode(const float* __restrict__ embed, const float* __restrict__ outIdx,
                       float* __restrict__ outQ, int nRows) {
  int gw = (blockIdx.x * blockDim.x + threadIdx.x) >> 6;
  int lane = threadIdx.x & 63;
  if (gw >= nRows) return;
  int bi = (int)outIdx[gw];
  const float4* src = (const float4*)(embed + (size_t)bi * DDIM);
  float4* dst = (float4*)(outQ + (size_t)gw * DDIM);
  dst[lane] = src[lane];
  dst[lane + 64] = src[lane + 64];
}

extern "C" void kernel_launch(void* const* d_in, const int* in_sizes, int n_in,
                              void* d_out, int out_size, void* d_ws, size_t ws_size,
                              hipStream_t stream) {
  const float* x = (const float*)d_in[0];
  const float* embed = (const float*)d_in[1];
  int nX = in_sizes[0];        // 16*2048*512
  int nRows = nX / DDIM;       // 32768
  int nRowBlocks = nRows / BM; // 128

  float* out = (float*)d_out;
  float* outIdx = out;
  float* outQ = out + nRows;

  size_t szA = (size_t)nRows * DDIM * sizeof(f16);              // 32 MiB
  size_t szB = (size_t)KCODES * DDIM * sizeof(f16);             // 4 MiB
  size_t szEsq = (size_t)KCODES * sizeof(float);                // 16 KiB
  size_t szPart = (size_t)nRows * NSPLIT * 2 * sizeof(float4);  // 2 MiB
  size_t szLA = (size_t)nRows * sizeof(int4);                   // 512 KiB
  size_t szLB = (size_t)nRows * sizeof(int);                    // 128 KiB
  size_t szFB = (size_t)CAPB * 8 * sizeof(double2);             // 512 KiB

  char* ws = (char*)d_ws;
  f16 *Ah, *Bh;
  float* esqh;
  float4* parts;
  int4* listA;
  int* listB;
  double2* fbParts;
  int* cnts;
  size_t needFull = szA + szB + szEsq + szPart + szLA + szLB + szFB + 64;
  if (ws_size >= needFull) {
    Ah = (f16*)ws;
    Bh = (f16*)(ws + szA);
    esqh = (float*)(ws + szA + szB);
    parts = (float4*)(ws + szA + szB + szEsq);
    listA = (int4*)(ws + szA + szB + szEsq + szPart);
    listB = (int*)(ws + szA + szB + szEsq + szPart + szLA);
    fbParts = (double2*)(ws + szA + szB + szEsq + szPart + szLA + szLB);
    cnts = (int*)(ws + szA + szB + szEsq + szPart + szLA + szLB + szFB);
  } else {
    // quantize region of d_out (64 MiB) holds Ah; decode overwrites it at end
    Ah = (f16*)outQ;
    Bh = (f16*)ws;
    esqh = (float*)(ws + szB);
    parts = (float4*)(ws + szB + szEsq);
    listA = (int4*)(ws + szB + szEsq + szPart);
    listB = (int*)(ws + szB + szEsq + szPart + szLA);
    fbParts = (double2*)(ws + szB + szEsq + szPart + szLA + szLB);
    cnts = (int*)(ws + szB + szEsq + szPart + szLA + szLB + szFB);
  }

  int n4x = nX / 4;
  int n4e = in_sizes[1] / 4;
  hipLaunchKernelGGL(convert_hi, dim3(2048), dim3(256), 0, stream, x, Ah, n4x);
  hipLaunchKernelGGL(convert_hi, dim3((n4e + 255) / 256), dim3(256), 0, stream, embed, Bh, n4e);
  hipLaunchKernelGGL(esq_kernel, dim3(KCODES / 4), dim3(256), 0, stream, embed, esqh);
  hipLaunchKernelGGL(zero2, dim3(1), dim3(1), 0, stream, cnts);
  hipLaunchKernelGGL(vq_main, dim3(nRowBlocks * NSPLIT), dim3(512), 0, stream,
                     Ah, Bh, esqh, parts, nRowBlocks);
  hipLaunchKernelGGL(reduce_top3, dim3(nRows / 256), dim3(256), 0, stream,
                     parts, outIdx, listA, listB, cnts, nRows);
  hipLaunchKernelGGL(fixupA, dim3(256), dim3(256), 0, stream, x, embed, cnts, listA, outIdx);
  hipLaunchKernelGGL(fixupB, dim3(1024), dim3(256), 0, stream, x, embed, cnts, listB, fbParts);
  hipLaunchKernelGGL(fixupB2, dim3(1), dim3(256), 0, stream, cnts, listB, fbParts, outIdx);
  hipLaunchKernelGGL(decode, dim3(nRows / 4), dim3(256), 0, stream,
                     embed, outIdx, outQ, nRows);
}